// Round 7
// baseline (48.946 us; speedup 1.0000x reference)
//
#include <hip/hip_runtime.h>

#define HH 256
#define WW 256
#define CC 64
#define NG 8
#define NE 32
#define PX 32           // pixels per block (8 per wave)
#define THRESH 15.0f

typedef float f32x4 __attribute__((ext_vector_type(4)));

// out layout: feats (8,256,256,65) floats, then mask (8,256,256) floats
#define FEATS_ELEMS ((size_t)NG * HH * WW * 65)

// per-wave strip: rows (yy*9+x), yy in {0,1} (img rows v-1,v), x in [0,9)
// (cols u0+8w-1 .. u0+8w+7); addr = (yy*9+x)*65 + c.  18*65 = 1170, pad to 1172
// so each wave's base (and its t-region) stays 16B-aligned.
#define STRIP_PAD 1172
#define STRIP_LOAD (CC * 2 * 9)   // 1152 elements = 18 per lane

__global__ __launch_bounds__(256, 5) void fused_sparse_encoder(
    const float* __restrict__ img,    // (64,256,256)
    const float* __restrict__ edges,  // (8,32,4)
    float* __restrict__ out)
{
#pragma clang fp contract(off)
    __shared__ float4 s_k1[NG * NE];          // e0v, e0u, dn0, dn1
    __shared__ float2 s_k2[NG * NE];          // e1v, e1u
    __shared__ float  s_k3[NG * NE];          // Lm
    __shared__ float  s_strip[4][STRIP_PAD];  // wave-private img strip / t tile
    __shared__ float  s_m[4][64];             // [wave][g*8+pxl] mask
    __shared__ float  s_p[4][64];             // [wave][g*8+pxl] pinfo

    const int tid  = threadIdx.x;
    const int w    = tid >> 6;
    const int lane = tid & 63;
    const int u0   = blockIdx.x * PX;
    const int v    = blockIdx.y;

    // ---- Phase A: per-edge precompute (256 threads = 256 edges) + ONLY barrier
    {
        const float4 e4 = reinterpret_cast<const float4*>(edges)[tid];
        const float e0v = e4.x * 256.0f;
        const float e0u = e4.y * 256.0f;
        const float e1v = e4.z * 256.0f;
        const float e1u = e4.w * 256.0f;
        const float d0 = e1v - e0v;
        const float d1 = e1u - e0u;
        const float L  = __fsqrt_rn(d0 * d0 + d1 * d1);
        const float Lm = fmaxf(L, 1e-4f);
        s_k1[tid] = make_float4(e0v, e0u, __fdiv_rn(d0, Lm), __fdiv_rn(d1, Lm));
        s_k2[tid] = make_float2(e1v, e1u);
        s_k3[tid] = Lm;
    }
    __syncthreads();
    // ---- everything below is wave-local: no further barriers ----

    // ---- Phase C-issue: wave strip loads into registers (in flight during B)
    const int gx0 = u0 + 8 * w - 1;
    float cbuf[18];
    #pragma unroll
    for (int t = 0; t < 18; ++t) {
        const int i  = lane + t * 64;          // < 1152
        const unsigned ui = (unsigned)i;
        const int c  = (int)(ui / 18u);
        const int r  = i - c * 18;
        const int yy = (r >= 9) ? 1 : 0;
        const int x  = r - yy * 9;
        const int gy = v - 1 + yy;
        const int gx = gx0 + x;
        float val = 0.0f;
        if (gy >= 0 && gx >= 0) {              // gy<=255, gx<=255 always
            val = img[((size_t)c * HH + gy) * WW + gx];
        }
        cbuf[t] = val;
    }

    // ---- Phase B: mask + pinfo; lane = (g, pxl) of this wave's 8 pixels
    {
        const int g   = lane >> 3;
        const int pxl = lane & 7;
        const float U = (float)(u0 + 8 * w + pxl);
        const float V = (float)v;
        float sm = 0.0f, cnt = 0.0f;
        bool any = false;
        for (int e = 0; e < NE; ++e) {
            const int idx = g * NE + e;
            const float4 k1 = s_k1[idx];
            const float2 k2 = s_k2[idx];
            const float  Lm = s_k3[idx];
            const float diff0 = V - k1.x;
            const float diff1 = U - k1.y;
            const float ndv = diff0 * k1.w - diff1 * k1.z;
            const float ddn = diff0 * k1.z + diff1 * k1.w;
            const float dd  = __fdiv_rn(ddn, Lm);
            const float r0sq = diff0 * diff0 + diff1 * diff1;
            const float f0 = V - k2.x;
            const float f1 = U - k2.y;
            const float r1sq = f0 * f0 + f1 * f1;
            const bool m = ((fabsf(ndv) <= THRESH) && (dd <= 1.0f) && (dd >= 0.0f))
                           || (r0sq <= 225.0f) || (r1sq <= 225.0f);
            if (m) {
                any = true;
                sm += fminf(dd, 1.0f - dd);
                cnt += 1.0f;
            }
        }
        const float pf = __fdiv_rn(sm, fmaxf(cnt, 1e-4f));
        const float mv = any ? 1.0f : 0.0f;
        s_m[w][lane] = mv;
        s_p[w][lane] = pf;
        out[FEATS_ELEMS + ((size_t)g * HH + v) * WW + (u0 + 8 * w + pxl)] = mv;
    }

    // ---- Phase C-commit: registers -> wave-private strip
    #pragma unroll
    for (int t = 0; t < 18; ++t) {
        const int i  = lane + t * 64;
        const unsigned ui = (unsigned)i;
        const int c  = (int)(ui / 18u);
        const int r  = i - c * 18;
        const int yy = (r >= 9) ? 1 : 0;
        const int x  = r - yy * 9;
        s_strip[w][(yy * 9 + x) * 65 + c] = cbuf[t];
    }
    // wave-local LDS: in-order per wave, compiler inserts lgkmcnt — no barrier

    // ---- Phase D1: 2x2 box sample; lane = channel, 8 px of this wave
    float sreg[8];
    #pragma unroll
    for (int i = 0; i < 8; ++i) {
        sreg[i] = s_strip[w][(i) * 65 + lane] * 0.25f
                + s_strip[w][(i + 1) * 65 + lane] * 0.25f
                + s_strip[w][(9 + i) * 65 + lane] * 0.25f
                + s_strip[w][(10 + i) * 65 + lane] * 0.25f;
    }

    // ---- Phase D2: transpose into t region (aliases strip rows; in-wave WAR safe)
    #pragma unroll
    for (int i = 0; i < 8; ++i) {
        s_strip[w][i * 65 + lane] = sreg[i];
    }

    // ---- Phase E: stream this wave's slice: 8 g x 130 float4 = 1040 stores
    {
        const size_t arow = ((size_t)v * WW + u0 + 8 * w);
        #pragma unroll
        for (int t = 0; t < 17; ++t) {
            const int j = lane + t * 64;
            if (j < 1040) {
                const unsigned uj = (unsigned)j;
                const int g  = (int)(uj / 130u);
                const int q  = j - g * 130;
                const int f  = q * 4;
                const int p0 = (int)((unsigned)f / 65u);
                const int b  = (p0 + 1) * 65 - f;   // elems jj<b-1: px p0; jj==b-1: pinfo; jj>=b: px p0+1
                const f32x4 tv = *reinterpret_cast<const f32x4*>(&s_strip[w][f]);
                const float m0  = s_m[w][g * 8 + p0];
                const float m1  = s_m[w][g * 8 + ((b < 4) ? (p0 + 1) : p0)];
                const float pi0 = s_p[w][g * 8 + p0];
                f32x4 r;
                r.x = ((b == 1) ? pi0 : tv.x) * ((0 < b) ? m0 : m1);
                r.y = ((b == 2) ? pi0 : tv.y) * ((1 < b) ? m0 : m1);
                r.z = ((b == 3) ? pi0 : tv.z) * ((2 < b) ? m0 : m1);
                r.w = ((b == 4) ? pi0 : tv.w) * ((3 < b) ? m0 : m1);
                float* gout = out + ((size_t)g * HH * WW + arow) * 65;
                __builtin_nontemporal_store(r, reinterpret_cast<f32x4*>(&gout[f]));
            }
        }
    }
}

extern "C" void kernel_launch(void* const* d_in, const int* in_sizes, int n_in,
                              void* d_out, int out_size, void* d_ws, size_t ws_size,
                              hipStream_t stream) {
    const float* img   = (const float*)d_in[0];
    const float* edges = (const float*)d_in[1];
    float* out = (float*)d_out;
    dim3 grid(WW / PX, HH);
    fused_sparse_encoder<<<grid, 256, 0, stream>>>(img, edges, out);
}

// Round 8
// 45.682 us; speedup vs baseline: 1.0714x; 1.0714x over previous
//
#include <hip/hip_runtime.h>

#define HH 256
#define WW 256
#define CC 64
#define NG 8
#define NE 32
#define PX 32           // pixels per tile; block = 2 tiles
#define THRESH 15.0f

typedef float f32x4 __attribute__((ext_vector_type(4)));

// out layout: feats (8,256,256,65) floats, then mask (8,256,256) floats
#define FEATS_ELEMS ((size_t)NG * HH * WW * 65)

// image tile in LDS: (yy,x): yy in {0,1} (img rows v-1,v), x in [0,33) (cols u0-1..u0+31)
// addr(yy,x,c) = (yy*33 + x)*65 + c ; 66*65 = 4290 floats.
// t tile aliases first 32*65 = 2080 floats: t(p,c) = p*65 + c (slot c=64 garbage -> pinfo).
#define IMG_ELEMS (CC * 2 * 33)   // 4224 loaded elements

__global__ __launch_bounds__(256, 4) void fused_sparse_encoder(
    const float* __restrict__ img,    // (64,256,256)
    const float* __restrict__ edges,  // (8,32,4)
    float* __restrict__ out)
{
#pragma clang fp contract(off)
    __shared__ float  s_buf[66 * 65];     // 17.16 KB, dual-use
    __shared__ float4 s_k1[NG * NE];      // e0v, e0u, dn0, dn1
    __shared__ float2 s_k2[NG * NE];      // e1v, e1u
    __shared__ float  s_k3[NG * NE];      // Lm
    __shared__ float  s_mask[2][NG * PX];
    __shared__ float  s_pinfo[2][NG * PX];

    const int tid  = threadIdx.x;
    const int wv   = tid >> 6;
    const int lane = tid & 63;
    const int v    = blockIdx.y;
    const int u00  = blockIdx.x * (2 * PX);   // block covers u00 .. u00+63, two tiles

    // ---- Phase A: per-edge precompute (256 threads = 256 edges)
    {
        const float4 e4 = reinterpret_cast<const float4*>(edges)[tid];
        const float e0v = e4.x * 256.0f;
        const float e0u = e4.y * 256.0f;
        const float e1v = e4.z * 256.0f;
        const float e1u = e4.w * 256.0f;
        const float d0 = e1v - e0v;
        const float d1 = e1u - e0u;
        const float L  = __fsqrt_rn(d0 * d0 + d1 * d1);
        const float Lm = fmaxf(L, 1e-4f);
        s_k1[tid] = make_float4(e0v, e0u, __fdiv_rn(d0, Lm), __fdiv_rn(d1, Lm));
        s_k2[tid] = make_float2(e1v, e1u);
        s_k3[tid] = Lm;
    }
    __syncthreads();

    // ---- Hoisted Phase-E per-thread constants (tile-invariant)
    int  e_f[3], e_p0[3], e_b[3];
    bool e_on[3];
    #pragma unroll
    for (int k = 0; k < 3; ++k) {
        const int q = tid + k * 256;
        e_on[k] = (q < 520);
        const int f  = q * 4;
        const int p0 = (int)((unsigned)f / 65u);
        e_f[k] = f; e_p0[k] = p0; e_b[k] = (p0 + 1) * 65 - f;
    }

    float cbuf[17];
    float sreg[8];

    auto issue_loads = [&](int u0) {
        #pragma unroll
        for (int t = 0; t < 17; ++t) {
            const int i = tid + t * 256;
            float val = 0.0f;
            if (i < IMG_ELEMS) {
                const int c  = i / 66;
                const int r  = i - c * 66;
                const int yy = r / 33;
                const int x  = r - yy * 33;
                const int gy = v - 1 + yy;
                const int gx = u0 - 1 + x;
                if (gy >= 0 && gx >= 0) {        // gy<=255, gx<=255 always
                    val = img[((size_t)c * HH + gy) * WW + gx];
                }
            }
            cbuf[t] = val;
        }
    };

    auto commit = [&]() {
        #pragma unroll
        for (int t = 0; t < 17; ++t) {
            const int i = tid + t * 256;
            if (i < IMG_ELEMS) {
                const int c  = i / 66;
                const int r  = i - c * 66;
                const int yy = r / 33;
                const int x  = r - yy * 33;
                s_buf[(yy * 33 + x) * 65 + c] = cbuf[t];
            }
        }
    };

    auto phaseB = [&](int u0, int pb) {
        const int px = tid & (PX - 1);
        const int g  = tid >> 5;
        const float U = (float)(u0 + px);
        const float V = (float)v;
        float sm = 0.0f, cnt = 0.0f;
        bool any = false;
        for (int e = 0; e < NE; ++e) {
            const int idx = g * NE + e;
            const float4 k1 = s_k1[idx];
            const float2 k2 = s_k2[idx];
            const float  Lm = s_k3[idx];
            const float diff0 = V - k1.x;
            const float diff1 = U - k1.y;
            const float ndv = diff0 * k1.w - diff1 * k1.z;
            const float ddn = diff0 * k1.z + diff1 * k1.w;
            const float dd  = __fdiv_rn(ddn, Lm);
            const float r0sq = diff0 * diff0 + diff1 * diff1;
            const float f0 = V - k2.x;
            const float f1 = U - k2.y;
            const float r1sq = f0 * f0 + f1 * f1;
            const bool m = ((fabsf(ndv) <= THRESH) && (dd <= 1.0f) && (dd >= 0.0f))
                           || (r0sq <= 225.0f) || (r1sq <= 225.0f);
            if (m) {
                any = true;
                sm += fminf(dd, 1.0f - dd);
                cnt += 1.0f;
            }
        }
        const float pf = __fdiv_rn(sm, fmaxf(cnt, 1e-4f));
        const float mv = any ? 1.0f : 0.0f;
        s_mask[pb][g * PX + px]  = mv;
        s_pinfo[pb][g * PX + px] = pf;
        out[FEATS_ELEMS + ((size_t)g * HH + v) * WW + (u0 + px)] = mv;
    };

    auto sample = [&]() {
        #pragma unroll
        for (int i = 0; i < 8; ++i) {
            const int p = wv * 8 + i;
            sreg[i] = s_buf[(p) * 65 + lane] * 0.25f
                    + s_buf[(p + 1) * 65 + lane] * 0.25f
                    + s_buf[(33 + p) * 65 + lane] * 0.25f
                    + s_buf[(34 + p) * 65 + lane] * 0.25f;
        }
    };

    auto transpose = [&]() {
        #pragma unroll
        for (int i = 0; i < 8; ++i) {
            s_buf[(wv * 8 + i) * 65 + lane] = sreg[i];
        }
    };

    auto storeE = [&](int u0, int pb) {
        for (int g = 0; g < NG; ++g) {
            float* gout = out + (((size_t)g * HH + v) * WW + u0) * 65;
            #pragma unroll
            for (int k = 0; k < 3; ++k) {
                if (e_on[k]) {
                    const int f  = e_f[k];
                    const int p0 = e_p0[k];
                    const int b  = e_b[k];
                    const f32x4 tv = *reinterpret_cast<const f32x4*>(&s_buf[f]);
                    const float m0  = s_mask[pb][g * PX + p0];
                    const float m1  = s_mask[pb][g * PX + ((b < 4) ? (p0 + 1) : p0)];
                    const float pi0 = s_pinfo[pb][g * PX + p0];
                    f32x4 r;
                    r.x = ((b == 1) ? pi0 : tv.x) * ((0 < b) ? m0 : m1);
                    r.y = ((b == 2) ? pi0 : tv.y) * ((1 < b) ? m0 : m1);
                    r.z = ((b == 3) ? pi0 : tv.z) * ((2 < b) ? m0 : m1);
                    r.w = ((b == 4) ? pi0 : tv.w) * ((3 < b) ? m0 : m1);
                    __builtin_nontemporal_store(r, reinterpret_cast<f32x4*>(&gout[f]));
                }
            }
        }
    };

    // ================= software-pipelined 2-tile schedule =================
    issue_loads(u00);            // T0 loads in flight
    phaseB(u00, 0);              // hides T0 load latency
    commit();                    // waits T0 vmcnt, fills s_buf
    issue_loads(u00 + PX);       // T1 loads in flight from here on
    __syncthreads();
    sample();
    __syncthreads();
    transpose();
    __syncthreads();
    storeE(u00, 0);              // store stream T0 (T1 loads still flying)
    phaseB(u00 + PX, 1);         // VALU under store drain + load latency
    __syncthreads();             // all waves done reading t-tile
    commit();                    // waits T1 vmcnt (mostly already landed)
    __syncthreads();
    sample();
    __syncthreads();
    transpose();
    __syncthreads();
    storeE(u00 + PX, 1);
}

extern "C" void kernel_launch(void* const* d_in, const int* in_sizes, int n_in,
                              void* d_out, int out_size, void* d_ws, size_t ws_size,
                              hipStream_t stream) {
    const float* img   = (const float*)d_in[0];
    const float* edges = (const float*)d_in[1];
    float* out = (float*)d_out;
    dim3 grid(WW / (2 * PX), HH);
    fused_sparse_encoder<<<grid, 256, 0, stream>>>(img, edges, out);
}

// Round 9
// 43.012 us; speedup vs baseline: 1.1380x; 1.0621x over previous
//
#include <hip/hip_runtime.h>

#define HH 256
#define WW 256
#define CC 64
#define NG 8
#define NE 32
#define PX 16           // pixels per block
#define THRESH 15.0f

typedef float f32x4 __attribute__((ext_vector_type(4)));

// out layout: feats (8,256,256,65) floats, then mask (8,256,256) floats
#define FEATS_ELEMS ((size_t)NG * HH * WW * 65)

// img tile: row r = yy*17 + x ; yy in {0,1} -> img rows v-1,v ; x in [0,17) -> cols u0-1..u0+15
// addr = r*65 + c  (stride 65 keeps commit writes bank-spread)
#define IMG_ROWS 34
#define IMG_ELEMS (IMG_ROWS * CC)   // 2176 loaded elements

__global__ __launch_bounds__(256, 6) void fused_sparse_encoder(
    const float* __restrict__ img,    // (64,256,256)
    const float* __restrict__ edges,  // (8,32,4)
    float* __restrict__ out)
{
#pragma clang fp contract(off)
    __shared__ __align__(16) float s_buf[IMG_ROWS * 65];  // 8.84 KB img tile
    __shared__ __align__(16) float s_t[PX * 65];          // 4.16 KB t tile (c=64 slot garbage)
    __shared__ float4 s_k1[NG * NE];                      // e0v, e0u, dn0, dn1
    __shared__ float2 s_k2[NG * NE];                      // e1v, e1u
    __shared__ float  s_k3[NG * NE];                      // Lm
    __shared__ float  s_m[NG * PX];
    __shared__ float  s_p[NG * PX];

    const int tid  = threadIdx.x;
    const int wv   = tid >> 6;
    const int lane = tid & 63;
    const int u0   = blockIdx.x * PX;
    const int v    = blockIdx.y;

    // ---- Phase A: per-edge precompute (256 threads = 256 edges)
    {
        const float4 e4 = reinterpret_cast<const float4*>(edges)[tid];
        const float e0v = e4.x * 256.0f;
        const float e0u = e4.y * 256.0f;
        const float e1v = e4.z * 256.0f;
        const float e1u = e4.w * 256.0f;
        const float d0 = e1v - e0v;
        const float d1 = e1u - e0u;
        const float L  = __fsqrt_rn(d0 * d0 + d1 * d1);
        const float Lm = fmaxf(L, 1e-4f);
        s_k1[tid] = make_float4(e0v, e0u, __fdiv_rn(d0, Lm), __fdiv_rn(d1, Lm));
        s_k2[tid] = make_float2(e1v, e1u);
        s_k3[tid] = Lm;
    }
    __syncthreads();

    // ---- Phase C-issue: img tile loads into registers (in flight during Phase B)
    float cbuf[9];
    #pragma unroll
    for (int t = 0; t < 9; ++t) {
        const int i = tid + t * 256;
        float val = 0.0f;
        if (i < IMG_ELEMS) {
            const int c  = i / IMG_ROWS;
            const int r  = i - c * IMG_ROWS;
            const int yy = (r >= 17) ? 1 : 0;
            const int x  = r - yy * 17;
            const int gy = v - 1 + yy;
            const int gx = u0 - 1 + x;
            if (gy >= 0 && gx >= 0) {        // gy<=255, gx<=255 always
                val = img[((size_t)c * HH + gy) * WW + gx];
            }
        }
        cbuf[t] = val;
    }

    // ---- Phase B: mask + pinfo, one (g,px) per thread for tid<128 (hides load latency)
    if (tid < 128) {
        const int px = tid & (PX - 1);
        const int g  = tid >> 4;
        const float U = (float)(u0 + px);
        const float V = (float)v;
        float sm = 0.0f, cnt = 0.0f;
        bool any = false;
        for (int e = 0; e < NE; ++e) {
            const int idx = g * NE + e;
            const float4 k1 = s_k1[idx];
            const float2 k2 = s_k2[idx];
            const float  Lm = s_k3[idx];
            const float diff0 = V - k1.x;
            const float diff1 = U - k1.y;
            const float ndv = diff0 * k1.w - diff1 * k1.z;
            const float ddn = diff0 * k1.z + diff1 * k1.w;
            const float dd  = __fdiv_rn(ddn, Lm);
            const float r0sq = diff0 * diff0 + diff1 * diff1;
            const float f0 = V - k2.x;
            const float f1 = U - k2.y;
            const float r1sq = f0 * f0 + f1 * f1;
            const bool m = ((fabsf(ndv) <= THRESH) && (dd <= 1.0f) && (dd >= 0.0f))
                           || (r0sq <= 225.0f) || (r1sq <= 225.0f);
            if (m) {
                any = true;
                sm += fminf(dd, 1.0f - dd);
                cnt += 1.0f;
            }
        }
        const float pf = __fdiv_rn(sm, fmaxf(cnt, 1e-4f));
        const float mv = any ? 1.0f : 0.0f;
        s_m[g * PX + px] = mv;
        s_p[g * PX + px] = pf;
        out[FEATS_ELEMS + ((size_t)g * HH + v) * WW + (u0 + px)] = mv;
    }

    // ---- Phase C-commit: registers -> LDS img tile
    #pragma unroll
    for (int t = 0; t < 9; ++t) {
        const int i = tid + t * 256;
        if (i < IMG_ELEMS) {
            const int c  = i / IMG_ROWS;
            const int r  = i - c * IMG_ROWS;
            const int yy = (r >= 17) ? 1 : 0;
            const int x  = r - yy * 17;
            s_buf[(yy * 17 + x) * 65 + c] = cbuf[t];
        }
    }
    __syncthreads();

    // ---- Phase D1: 2x2 box sample; wave wv owns pixels [4wv, 4wv+4), lane = channel
    float sreg[4];
    #pragma unroll
    for (int i = 0; i < 4; ++i) {
        const int p = wv * 4 + i;
        sreg[i] = s_buf[(p) * 65 + lane] * 0.25f
                + s_buf[(p + 1) * 65 + lane] * 0.25f
                + s_buf[(17 + p) * 65 + lane] * 0.25f
                + s_buf[(18 + p) * 65 + lane] * 0.25f;
    }

    // ---- Phase D2: transpose into separate t tile (no alias -> no extra barrier)
    #pragma unroll
    for (int i = 0; i < 4; ++i) {
        s_t[(wv * 4 + i) * 65 + lane] = sreg[i];
    }
    __syncthreads();

    // ---- Phase E: stream 16*65 = 1040 floats (260 quads) per g, aligned + contiguous.
    // quad q0 = tid (all 256), plus q1 = tid+256 for tid<4.
    const int f0  = tid * 4;
    const int p00 = (int)((unsigned)f0 / 65u);
    const int b0  = (p00 + 1) * 65 - f0;
    const int pA0 = p00;
    const int pB0 = (b0 < 4) ? (p00 + 1) : p00;

    const bool on1 = (tid < 4);
    const int f1  = (tid + 256) * 4;
    const int p01 = (int)((unsigned)f1 / 65u);
    const int b1  = (p01 + 1) * 65 - f1;
    const int pA1 = p01;
    const int pB1 = (b1 < 4) ? (p01 + 1) : p01;

    const f32x4 tv0 = *reinterpret_cast<const f32x4*>(&s_t[f0]);
    f32x4 tv1;
    if (on1) tv1 = *reinterpret_cast<const f32x4*>(&s_t[f1]);

    for (int g = 0; g < NG; ++g) {
        float* gout = out + (((size_t)g * HH + v) * WW + u0) * 65;
        {
            const float m0 = s_m[g * PX + pA0];
            const float m1 = s_m[g * PX + pB0];
            const float pi = s_p[g * PX + pA0];
            f32x4 r;
            r.x = ((b0 == 1) ? pi : tv0.x) * ((0 < b0) ? m0 : m1);
            r.y = ((b0 == 2) ? pi : tv0.y) * ((1 < b0) ? m0 : m1);
            r.z = ((b0 == 3) ? pi : tv0.z) * ((2 < b0) ? m0 : m1);
            r.w = ((b0 == 4) ? pi : tv0.w) * ((3 < b0) ? m0 : m1);
            __builtin_nontemporal_store(r, reinterpret_cast<f32x4*>(&gout[f0]));
        }
        if (on1) {
            const float m0 = s_m[g * PX + pA1];
            const float m1 = s_m[g * PX + pB1];
            const float pi = s_p[g * PX + pA1];
            f32x4 r;
            r.x = ((b1 == 1) ? pi : tv1.x) * ((0 < b1) ? m0 : m1);
            r.y = ((b1 == 2) ? pi : tv1.y) * ((1 < b1) ? m0 : m1);
            r.z = ((b1 == 3) ? pi : tv1.z) * ((2 < b1) ? m0 : m1);
            r.w = ((b1 == 4) ? pi : tv1.w) * ((3 < b1) ? m0 : m1);
            __builtin_nontemporal_store(r, reinterpret_cast<f32x4*>(&gout[f1]));
        }
    }
}

extern "C" void kernel_launch(void* const* d_in, const int* in_sizes, int n_in,
                              void* d_out, int out_size, void* d_ws, size_t ws_size,
                              hipStream_t stream) {
    const float* img   = (const float*)d_in[0];
    const float* edges = (const float*)d_in[1];
    float* out = (float*)d_out;
    dim3 grid(WW / PX, HH);
    fused_sparse_encoder<<<grid, 256, 0, stream>>>(img, edges, out);
}